// Round 10
// baseline (137.146 us; speedup 1.0000x reference)
//
#include <hip/hip_runtime.h>
#include <hip/hip_bf16.h>

// GCN layer: agg = segment_sum(feats[src], dst); h = relu(agg@W+b) + relu(feats@Wr+br);
// out = batchnorm(h) over node dim (biased var, eps=1e-5) * gamma + beta.
// N=100000 nodes, E=1600000 edges, F=64.
//
// R10: XCD-lane split reverted (R9 prediction failed). PB=32768 (49 partition
// blocks, 2-pass read) -> 4x longer slot runs, ~2x less partial-line write traffic.
// mv fused into the bucket kernel (k_gmv): gather accumulators -> bf16 LDS tile ->
// waves 0-3 MFMA; kills the 25.6MB agg round-trip + one launch. Gather inner loop
// re-vectorized: dwordx2 per lane, 16 lanes/edge, 4 edges/wave-iter.

typedef __attribute__((ext_vector_type(8))) short short8;
typedef __attribute__((ext_vector_type(4))) float f32x4;

constexpr int BKT  = 64;           // nodes per bucket (dloc 6 bits | src 17 bits)
constexpr int NBKT_MAX = 2048;
constexpr int SCAP = 1536;         // per-bucket slot capacity (mean 1024)
constexpr int PB   = 32768;        // edges per partition batch (long runs)
constexpr int CAST_BLKS = 800;     // 800 x 1024 threads >= 800000 short8 groups

static __device__ __forceinline__ float bfbits_lo(unsigned u) {
    union { unsigned u; float f; } c; c.u = u << 16; return c.f;
}
static __device__ __forceinline__ float bfbits_hi(unsigned u) {
    union { unsigned u; float f; } c; c.u = u & 0xffff0000u; return c.f;
}
static __device__ __forceinline__ short bf16r(float x) {
    __hip_bfloat16 h = __float2bfloat16(x);   // RNE
    union { __hip_bfloat16 h; short s; } c; c.h = h; return c.s;
}
static __device__ __forceinline__ unsigned bf16pair(float x, float y) {
    return (unsigned)(unsigned short)bf16r(x) | ((unsigned)(unsigned short)bf16r(y) << 16);
}

// ---- fused prep+partition (role-split blocks, all 1024 threads) ----
// blocks [0,nbatch): partition edges into fixed bucket slots (2-pass, direct scatter)
// blocks [nbatch, nbatch+CAST_BLKS): feats fp32->bf16
// block  nbatch+CAST_BLKS: W/Wr MFMA B-fragment pack
__global__ __launch_bounds__(1024) void k_prep_part(
    const int* __restrict__ src, const int* __restrict__ dst,
    int* __restrict__ cursor, unsigned* __restrict__ pk_slots,
    int n_edges, int nbatch, int nbkt,
    const float* __restrict__ feats, unsigned short* __restrict__ feats_h, int total8,
    const float* __restrict__ W, const float* __restrict__ Wr,
    short* __restrict__ Wpk, short* __restrict__ Wrpk)
{
    __shared__ int hist[NBKT_MAX], basei[NBKT_MAX], cnt2[NBKT_MAX];
    const int bid = blockIdx.x;
    const int tid = threadIdx.x;
    if (bid < nbatch) {
        const int e0 = bid * PB;
        const int e1 = (e0 + PB < n_edges) ? e0 + PB : n_edges;
        for (int i = tid; i < nbkt; i += 1024) { hist[i] = 0; cnt2[i] = 0; }
        __syncthreads();
        for (int e = e0 + tid; e < e1; e += 1024)
            atomicAdd(&hist[dst[e] >> 6], 1);
        __syncthreads();
        for (int i = tid; i < nbkt; i += 1024) {
            const int c = hist[i];
            basei[i] = (c > 0) ? atomicAdd(&cursor[i], c) : 0;
        }
        __syncthreads();
        for (int e = e0 + tid; e < e1; e += 1024) {
            const int d = dst[e];
            const int s = src[e];
            const int bb = d >> 6;
            const int pos = basei[bb] + atomicAdd(&cnt2[bb], 1);
            if (pos < SCAP)                       // overflow guard (16-sigma headroom)
                pk_slots[(size_t)bb * SCAP + pos] =
                    ((unsigned)(d & 63) << 17) | (unsigned)s;
        }
    } else if (bid < nbatch + CAST_BLKS) {
        const int cb = bid - nbatch;
        for (int i = cb * 1024 + tid; i < total8; i += CAST_BLKS * 1024) {
            float4 v0 = ((const float4*)feats)[i * 2];
            float4 v1 = ((const float4*)feats)[i * 2 + 1];
            short8 o;
            o[0] = bf16r(v0.x); o[1] = bf16r(v0.y); o[2] = bf16r(v0.z); o[3] = bf16r(v0.w);
            o[4] = bf16r(v1.x); o[5] = bf16r(v1.y); o[6] = bf16r(v1.z); o[7] = bf16r(v1.w);
            ((short8*)feats_h)[i] = o;
        }
    } else {
        // pack W/Wr into MFMA B-fragment layout (verified R3):
        // packed[((s*4+t)*64+lane)*8+j] = W[(s*32+(lane>>4)*8+j)*64 + (t*16+(lane&15))]
        for (int idx = tid; idx < 8192; idx += 1024) {
            const int m = idx >> 12;
            const int rem = idx & 4095;
            const int j = rem & 7;
            const int q = rem >> 3;
            const int lane = q & 63;
            const int st = q >> 6;
            const int s = st >> 2;
            const int t = st & 3;
            const int k = s * 32 + (lane >> 4) * 8 + j;
            const int n = t * 16 + (lane & 15);
            const float v = (m == 0) ? W[k * 64 + n] : Wr[k * 64 + n];
            short* out = (m == 0) ? Wpk : Wrpk;
            out[rem] = bf16r(v);
        }
    }
}

// ---- fused bucket kernel: node-sort + gather + MFMA matvec + BN partials ----
// 512 thr (8 waves). Phase A: sort bucket edges to per-node lists in LDS (2-pass
// global read, no raw staging). Phase B: wave w gathers nodes w*8..w*8+7; each
// edge is read by 16 lanes x dwordx2 (4 edges/iter, 4 loads in flight); result
// rows stored bf16 in aggL[64][72] (144B stride: bank-rotated, 16B-aligned).
// Phase C: waves 0-3 run the dual MFMA matvec on the block's 64 rows.
__global__ __launch_bounds__(512) void k_gmv(
    const unsigned short* __restrict__ feats_h, const int* __restrict__ cursor,
    const unsigned* __restrict__ pk_slots,
    const short* __restrict__ Wpk, const short* __restrict__ Wrpk,
    const float* __restrict__ b, const float* __restrict__ br,
    float* __restrict__ h, float* __restrict__ bnacc, int n_nodes)
{
    __shared__ unsigned srt[SCAP];          // 6 KB
    __shared__ short aggL[64 * 72];         // 9.2 KB, row stride 72 shorts = 144 B
    __shared__ int cnt[BKT], cnt2[BKT], noff[BKT + 1];
    __shared__ float ssum[64], ssq[64];
    const int bkt = blockIdx.x;
    const int tid = threadIdx.x;
    int m = cursor[bkt]; if (m > SCAP) m = SCAP;
    const unsigned* gsl = pk_slots + (size_t)bkt * SCAP;

    if (tid < BKT) { cnt[tid] = 0; cnt2[tid] = 0; }
    if (tid < 64)  { ssum[tid] = 0.f; ssq[tid] = 0.f; }
    __syncthreads();

    // phase A: hist (pass 1)
    for (int i = tid; i < m; i += 512)
        atomicAdd(&cnt[gsl[i] >> 17], 1);
    __syncthreads();
    if (tid < 64) {                         // wave-0 inclusive shfl scan, 64 bins
        int v = cnt[tid];
        #pragma unroll
        for (int off = 1; off < 64; off <<= 1) {
            const int y = __shfl_up(v, off);
            if (tid >= off) v += y;
        }
        noff[tid + 1] = v;
        if (tid == 0) noff[0] = 0;
    }
    __syncthreads();
    // phase A: scatter (pass 2, re-read global — L2/L3 hot)
    for (int i = tid; i < m; i += 512) {
        const unsigned p = gsl[i];
        const int d = p >> 17;
        srt[noff[d] + atomicAdd(&cnt2[d], 1)] = p & 0x1ffffu;
    }
    __syncthreads();

    // phase B: gather, 8 nodes per wave
    const int wave = tid >> 6;
    const int lane = tid & 63;
    const int slot = lane >> 4;             // edge slot 0..3
    const int q    = lane & 15;             // column quarter: cols 4q..4q+3
    #pragma unroll 1
    for (int k = 0; k < 8; k++) {
        const int nl = wave * 8 + k;
        const int n  = bkt * BKT + nl;
        if (n >= n_nodes) break;
        const int beg = noff[nl], end = noff[nl + 1];
        float a0 = 0.f, a1 = 0.f, a2 = 0.f, a3 = 0.f;
        int base = beg;
        for (; base + 16 <= end; base += 16) {          // 4 unmasked 4-edge groups
            #pragma unroll
            for (int g = 0; g < 4; g++) {
                const unsigned s = srt[base + 4 * g + slot];
                const uint2 v = *(const uint2*)(feats_h + (size_t)s * 64 + q * 4);
                a0 += bfbits_lo(v.x); a1 += bfbits_hi(v.x);
                a2 += bfbits_lo(v.y); a3 += bfbits_hi(v.y);
            }
        }
        if (base < end) {                               // masked tail (up to 15 edges)
            #pragma unroll
            for (int g = 0; g < 4; g++) {
                const int e = base + 4 * g + slot;
                const bool vd = e < end;
                const unsigned s = srt[vd ? e : beg];
                const uint2 v = *(const uint2*)(feats_h + (size_t)s * 64 + q * 4);
                a0 += vd ? bfbits_lo(v.x) : 0.f;
                a1 += vd ? bfbits_hi(v.x) : 0.f;
                a2 += vd ? bfbits_lo(v.y) : 0.f;
                a3 += vd ? bfbits_hi(v.y) : 0.f;
            }
        }
        a0 += __shfl_xor(a0, 16); a0 += __shfl_xor(a0, 32);
        a1 += __shfl_xor(a1, 16); a1 += __shfl_xor(a1, 32);
        a2 += __shfl_xor(a2, 16); a2 += __shfl_xor(a2, 32);
        a3 += __shfl_xor(a3, 16); a3 += __shfl_xor(a3, 32);
        if (slot == 0) {
            uint2 o;
            o.x = bf16pair(a0, a1);
            o.y = bf16pair(a2, a3);
            *(uint2*)(&aggL[nl * 72 + q * 4]) = o;      // 8B aligned (144*nl + 8q)
        }
    }
    __syncthreads();

    // phase C: waves 0-3, 16 rows each (block-local rows 0..63)
    if (wave < 4) {
        short8 wf[8], wrf[8];
        #pragma unroll
        for (int i = 0; i < 8; i++) {
            wf[i]  = *(const short8*)(Wpk  + (i * 64 + lane) * 8);
            wrf[i] = *(const short8*)(Wrpk + (i * 64 + lane) * 8);
        }
        float bt[4], brt[4];
        #pragma unroll
        for (int t = 0; t < 4; t++) {
            bt[t]  = b [t * 16 + (lane & 15)];
            brt[t] = br[t * 16 + (lane & 15)];
        }
        const int rl0 = wave * 16;
        const int arow_l = rl0 + (lane & 15);
        const int kb = (lane >> 4) * 8;
        int grow = bkt * BKT + arow_l;
        if (grow >= n_nodes) grow = n_nodes - 1;        // clamped rows -> discarded

        short8 aggA[2], feaA[2];
        #pragma unroll
        for (int s = 0; s < 2; s++) {
            aggA[s] = *(const short8*)(&aggL[arow_l * 72 + s * 32 + kb]);
            feaA[s] = *(const short8*)(feats_h + (size_t)grow * 64 + s * 32 + kb);
        }
        #pragma unroll
        for (int t = 0; t < 4; t++) {
            f32x4 c1 = {0.f, 0.f, 0.f, 0.f};
            f32x4 c2 = {0.f, 0.f, 0.f, 0.f};
            c1 = __builtin_amdgcn_mfma_f32_16x16x32_bf16(aggA[0], wf [t],     c1, 0, 0, 0);
            c1 = __builtin_amdgcn_mfma_f32_16x16x32_bf16(aggA[1], wf [4 + t], c1, 0, 0, 0);
            c2 = __builtin_amdgcn_mfma_f32_16x16x32_bf16(feaA[0], wrf[t],     c2, 0, 0, 0);
            c2 = __builtin_amdgcn_mfma_f32_16x16x32_bf16(feaA[1], wrf[4 + t], c2, 0, 0, 0);
            const int col = t * 16 + (lane & 15);
            float ls = 0.f, lq = 0.f;
            #pragma unroll
            for (int r = 0; r < 4; r++) {
                const int row = bkt * BKT + rl0 + (lane >> 4) * 4 + r;
                const float hv = fmaxf(c1[r] + bt[t], 0.f) + fmaxf(c2[r] + brt[t], 0.f);
                if (row < n_nodes) {
                    h[(size_t)row * 64 + col] = hv;
                    ls += hv;
                    lq += hv * hv;
                }
            }
            ls += __shfl_xor(ls, 16); ls += __shfl_xor(ls, 32);
            lq += __shfl_xor(lq, 16); lq += __shfl_xor(lq, 32);
            if ((lane >> 4) == 0) {
                atomicAdd(&ssum[col], ls);
                atomicAdd(&ssq[col], lq);
            }
        }
    }
    __syncthreads();
    if (tid < 64) {
        atomicAdd(&bnacc[tid], ssum[tid]);
        atomicAdd(&bnacc[64 + tid], ssq[tid]);
    }
}

// ---- BN scale/shift + apply in-place ----
__global__ __launch_bounds__(256) void k_bnapply(
    float* __restrict__ h, const float* __restrict__ bnacc,
    const float* __restrict__ gamma, const float* __restrict__ beta,
    int total4, float inv_n)
{
    __shared__ float ssc[64], ssh[64];
    if (threadIdx.x < 64) {
        const int t = threadIdx.x;
        const float mean = bnacc[t] * inv_n;
        const float var  = bnacc[64 + t] * inv_n - mean * mean;  // biased
        const float sc = gamma[t] * rsqrtf(var + 1e-5f);
        ssc[t] = sc;
        ssh[t] = beta[t] - mean * sc;
    }
    __syncthreads();
    for (int i = blockIdx.x * blockDim.x + threadIdx.x; i < total4;
         i += gridDim.x * blockDim.x) {
        float4 v = ((float4*)h)[i];
        const int j = (i & 15) << 2;
        v.x = v.x * ssc[j + 0] + ssh[j + 0];
        v.y = v.y * ssc[j + 1] + ssh[j + 1];
        v.z = v.z * ssc[j + 2] + ssh[j + 2];
        v.w = v.w * ssc[j + 3] + ssh[j + 3];
        ((float4*)h)[i] = v;
    }
}

extern "C" void kernel_launch(void* const* d_in, const int* in_sizes, int n_in,
                              void* d_out, int out_size, void* d_ws, size_t ws_size,
                              hipStream_t stream)
{
    const float* feats = (const float*)d_in[0];
    const int*   src   = (const int*)  d_in[1];
    const int*   dst   = (const int*)  d_in[2];
    const float* W     = (const float*)d_in[3];
    const float* b     = (const float*)d_in[4];
    const float* Wr    = (const float*)d_in[5];
    const float* br    = (const float*)d_in[6];
    const float* gamma = (const float*)d_in[7];
    const float* beta  = (const float*)d_in[8];

    const int n_nodes = in_sizes[0] / 64;            // 100000 (< 2^17)
    const int n_edges = in_sizes[1];
    const int nbkt    = (n_nodes + BKT - 1) / BKT;   // 1563 (<= NBKT_MAX)
    const int nbatch  = (n_edges + PB - 1) / PB;     // 49

    // ws: cursor[2048] | bnacc[128] | pk_slots[nbkt*SCAP u32 ~9.6MB] |
    //     feats_h[N*64 u16 12.8MB] | Wpk[4096 s16] | Wrpk[4096 s16]
    int*      cursor   = (int*)d_ws;
    float*    bnacc    = (float*)(cursor + NBKT_MAX);
    unsigned* pk_slots = (unsigned*)(bnacc + 128);
    unsigned short* feats_h = (unsigned short*)(pk_slots + (size_t)nbkt * SCAP);
    short*    Wpk      = (short*)(feats_h + (size_t)n_nodes * 64);
    short*    Wrpk     = Wpk + 4096;
    float*    h        = (float*)d_out;

    // zero cursor + bnacc (contiguous)
    hipMemsetAsync(cursor, 0, (size_t)(NBKT_MAX + 128) * sizeof(int), stream);

    k_prep_part<<<nbatch + CAST_BLKS + 1, 1024, 0, stream>>>(
        src, dst, cursor, pk_slots, n_edges, nbatch, nbkt,
        feats, feats_h, n_nodes * 8, W, Wr, Wpk, Wrpk);
    k_gmv<<<nbkt, 512, 0, stream>>>(feats_h, cursor, pk_slots, Wpk, Wrpk,
                                    b, br, h, bnacc, n_nodes);
    k_bnapply<<<2048, 256, 0, stream>>>(h, bnacc, gamma, beta, n_nodes * 16,
                                        1.f / (float)n_nodes);
}

// Round 11
// 101.217 us; speedup vs baseline: 1.3550x; 1.3550x over previous
//
#include <hip/hip_runtime.h>
#include <hip/hip_bf16.h>

// GCN layer: agg = segment_sum(feats[src], dst); h = relu(agg@W+b) + relu(feats@Wr+br);
// out = batchnorm(h) over node dim (biased var, eps=1e-5) * gamma + beta.
// N=100000 nodes, E=1600000 edges, F=64.
//
// R11 = R8 (best known: 103us) + two contained tweaks:
//  - k_gsort gather loop: 16-lane x 8B (uint2) per edge, 4 edge-slots/wave ->
//    half the loads/LDS-reads/addr-VALU of the 32-lane x 4B scheme.
//  - 64-bin scan via wave-0 shfl (2 barriers instead of 12).
// R10's lessons kept: partition stays register-staged with 196 blocks (PB=8192);
// gather and MFMA mv stay SEPARATE kernels.

typedef __attribute__((ext_vector_type(8))) short short8;
typedef __attribute__((ext_vector_type(4))) float f32x4;

constexpr int BKT  = 64;           // nodes per bucket (dloc 6 bits | src 17 bits)
constexpr int NBKT_MAX = 2048;
constexpr int SCAP = 1536;         // per-bucket slot capacity (mean 1024)
constexpr int PB   = 8192;         // edges per partition batch
constexpr int CAST_BLKS = 800;     // 800 x 1024 threads >= 800000 short8 groups

static __device__ __forceinline__ float bfbits_lo(unsigned u) {
    union { unsigned u; float f; } c; c.u = u << 16; return c.f;
}
static __device__ __forceinline__ float bfbits_hi(unsigned u) {
    union { unsigned u; float f; } c; c.u = u & 0xffff0000u; return c.f;
}
static __device__ __forceinline__ short bf16r(float x) {
    __hip_bfloat16 h = __float2bfloat16(x);   // RNE
    union { __hip_bfloat16 h; short s; } c; c.h = h; return c.s;
}
static __device__ __forceinline__ unsigned bf16pair(float x, float y) {
    return (unsigned)(unsigned short)bf16r(x) | ((unsigned)(unsigned short)bf16r(y) << 16);
}

// ---- fused prep+partition (role-split blocks, all 1024 threads) — R8 form ----
// blocks [0,nbatch): partition edges into fixed bucket slots (register-staged)
// blocks [nbatch, nbatch+CAST_BLKS): feats fp32->bf16
// block  nbatch+CAST_BLKS: W/Wr MFMA B-fragment pack
__global__ __launch_bounds__(1024) void k_prep_part(
    const int* __restrict__ src, const int* __restrict__ dst,
    int* __restrict__ cursor, unsigned* __restrict__ pk_slots,
    int n_edges, int nbatch, int nbkt,
    const float* __restrict__ feats, unsigned short* __restrict__ feats_h, int total8,
    const float* __restrict__ W, const float* __restrict__ Wr,
    short* __restrict__ Wpk, short* __restrict__ Wrpk)
{
    __shared__ int hist[NBKT_MAX], basei[NBKT_MAX], cnt2[NBKT_MAX];
    const int bid = blockIdx.x;
    const int tid = threadIdx.x;
    if (bid < nbatch) {
        const int e0 = bid * PB;
        for (int i = tid; i < nbkt; i += 1024) { hist[i] = 0; cnt2[i] = 0; }
        __syncthreads();
        unsigned pk[8]; unsigned short bb8[8];
        #pragma unroll
        for (int i = 0; i < 8; i++) {
            const int e = e0 + i * 1024 + tid;
            if (e < n_edges) {
                const int d = dst[e];
                const int s = src[e];
                const int bb = d >> 6;
                bb8[i] = (unsigned short)bb;
                pk[i] = ((unsigned)(d & 63) << 17) | (unsigned)s;
                atomicAdd(&hist[bb], 1);
            } else bb8[i] = 0xffff;
        }
        __syncthreads();
        for (int i = tid; i < nbkt; i += 1024) {
            const int c = hist[i];
            basei[i] = (c > 0) ? atomicAdd(&cursor[i], c) : 0;
        }
        __syncthreads();
        #pragma unroll
        for (int i = 0; i < 8; i++) {
            if (bb8[i] != 0xffff) {
                const int bb = bb8[i];
                const int pos = basei[bb] + atomicAdd(&cnt2[bb], 1);
                if (pos < SCAP)                       // overflow guard (never in practice)
                    pk_slots[(size_t)bb * SCAP + pos] = pk[i];
            }
        }
    } else if (bid < nbatch + CAST_BLKS) {
        const int cb = bid - nbatch;
        for (int i = cb * 1024 + tid; i < total8; i += CAST_BLKS * 1024) {
            float4 v0 = ((const float4*)feats)[i * 2];
            float4 v1 = ((const float4*)feats)[i * 2 + 1];
            short8 o;
            o[0] = bf16r(v0.x); o[1] = bf16r(v0.y); o[2] = bf16r(v0.z); o[3] = bf16r(v0.w);
            o[4] = bf16r(v1.x); o[5] = bf16r(v1.y); o[6] = bf16r(v1.z); o[7] = bf16r(v1.w);
            ((short8*)feats_h)[i] = o;
        }
    } else {
        // pack W/Wr into MFMA B-fragment layout (verified R3):
        // packed[((s*4+t)*64+lane)*8+j] = W[(s*32+(lane>>4)*8+j)*64 + (t*16+(lane&15))]
        for (int idx = tid; idx < 8192; idx += 1024) {
            const int m = idx >> 12;
            const int rem = idx & 4095;
            const int j = rem & 7;
            const int q = rem >> 3;
            const int lane = q & 63;
            const int st = q >> 6;
            const int s = st >> 2;
            const int t = st & 3;
            const int k = s * 32 + (lane >> 4) * 8 + j;
            const int n = t * 16 + (lane & 15);
            const float v = (m == 0) ? W[k * 64 + n] : Wr[k * 64 + n];
            short* out = (m == 0) ? Wpk : Wrpk;
            out[rem] = bf16r(v);
        }
    }
}

// ---- fused per-bucket node-sort + gather: 512 thr (8 waves), 4 blocks/CU ----
// Sorts the bucket's ~1024 edges to per-node lists in LDS, then wave w gathers
// nodes w*8..w*8+7: each edge read by 16 lanes x uint2 (8B), 4 edge-slots/wave,
// 4 groups/iter (16 edges, 4 loads in flight/lane). Unmasked main + masked tail.
// Writes bf16 agg rows into d_out row-slots (first 128B of each 256B slot).
__global__ __launch_bounds__(512) void k_gsort(
    const unsigned short* __restrict__ feats_h, const int* __restrict__ cursor,
    const unsigned* __restrict__ pk_slots, unsigned short* __restrict__ aggh,
    int n_nodes)
{
    __shared__ unsigned raw[SCAP];        // 6 KB
    __shared__ unsigned srt[SCAP];        // 6 KB
    __shared__ int cnt[BKT], cnt2[BKT], noff[BKT + 1];
    const int bkt = blockIdx.x;
    const int tid = threadIdx.x;
    int m = cursor[bkt]; if (m > SCAP) m = SCAP;
    const unsigned* gsl = pk_slots + (size_t)bkt * SCAP;

    if (tid < BKT) { cnt[tid] = 0; cnt2[tid] = 0; }
    __syncthreads();
    for (int i = tid; i < m; i += 512) {
        const unsigned p = gsl[i];
        raw[i] = p;
        atomicAdd(&cnt[p >> 17], 1);
    }
    __syncthreads();
    if (tid < 64) {                       // wave-0 inclusive shfl scan over 64 bins
        int v = cnt[tid];
        #pragma unroll
        for (int off = 1; off < 64; off <<= 1) {
            const int y = __shfl_up(v, off);
            if (tid >= off) v += y;
        }
        noff[tid + 1] = v;
        if (tid == 0) noff[0] = 0;
    }
    __syncthreads();
    for (int i = tid; i < m; i += 512) {
        const unsigned p = raw[i];
        const int d = p >> 17;
        srt[noff[d] + atomicAdd(&cnt2[d], 1)] = p & 0x1ffffu;
    }
    __syncthreads();

    // gather: 8 nodes per wave; 16 lanes x 8B per edge, 4 edge slots
    const int wave = tid >> 6;
    const int lane = tid & 63;
    const int slot = lane >> 4;           // edge slot 0..3
    const int q    = lane & 15;           // column group: cols 4q..4q+3
    #pragma unroll 1
    for (int k = 0; k < 8; k++) {
        const int nl = wave * 8 + k;
        const int n  = bkt * BKT + nl;
        if (n >= n_nodes) break;
        const int beg = noff[nl], end = noff[nl + 1];
        float a0 = 0.f, a1 = 0.f, a2 = 0.f, a3 = 0.f;
        int base = beg;
        for (; base + 16 <= end; base += 16) {      // unmasked: 4 groups x 4 edges
            #pragma unroll
            for (int g = 0; g < 4; g++) {
                const unsigned s = srt[base + 4 * g + slot];
                const uint2 v = *(const uint2*)(feats_h + (size_t)s * 64 + q * 4);
                a0 += bfbits_lo(v.x); a1 += bfbits_hi(v.x);
                a2 += bfbits_lo(v.y); a3 += bfbits_hi(v.y);
            }
        }
        if (base < end) {                           // single masked tail block
            #pragma unroll
            for (int g = 0; g < 4; g++) {
                const int e = base + 4 * g + slot;
                const bool vd = e < end;
                const unsigned s = srt[vd ? e : beg];
                const uint2 v = *(const uint2*)(feats_h + (size_t)s * 64 + q * 4);
                a0 += vd ? bfbits_lo(v.x) : 0.f;
                a1 += vd ? bfbits_hi(v.x) : 0.f;
                a2 += vd ? bfbits_lo(v.y) : 0.f;
                a3 += vd ? bfbits_hi(v.y) : 0.f;
            }
        }
        a0 += __shfl_xor(a0, 16); a0 += __shfl_xor(a0, 32);
        a1 += __shfl_xor(a1, 16); a1 += __shfl_xor(a1, 32);
        a2 += __shfl_xor(a2, 16); a2 += __shfl_xor(a2, 32);
        a3 += __shfl_xor(a3, 16); a3 += __shfl_xor(a3, 32);
        if (slot == 0) {
            uint2 o;
            o.x = bf16pair(a0, a1);
            o.y = bf16pair(a2, a3);
            *(uint2*)(aggh + (size_t)n * 128 + q * 4) = o;   // 8B aligned
        }
    }
}

// ---- dual matvec via MFMA + relu + residual + BN partials (proven R3/R6) ----
// aggh and h alias d_out; each wave reads its 16 rows before writing them.
__global__ __launch_bounds__(512) void k_mv(
    const unsigned short* aggh, const unsigned short* __restrict__ feats_h,
    const short* __restrict__ Wpk, const short* __restrict__ Wrpk,
    const float* __restrict__ b, const float* __restrict__ br,
    float* h, float* __restrict__ bnacc, int n_nodes)
{
    __shared__ float ssum[64], ssq[64];
    const int tid = threadIdx.x;
    const int wave = tid >> 6;
    const int lane = tid & 63;
    if (tid < 64) { ssum[tid] = 0.f; ssq[tid] = 0.f; }
    __syncthreads();

    short8 wf[8], wrf[8];
    #pragma unroll
    for (int i = 0; i < 8; i++) {
        wf[i]  = *(const short8*)(Wpk  + (i * 64 + lane) * 8);
        wrf[i] = *(const short8*)(Wrpk + (i * 64 + lane) * 8);
    }
    float bt[4], brt[4];
    #pragma unroll
    for (int t = 0; t < 4; t++) {
        bt[t]  = b [t * 16 + (lane & 15)];
        brt[t] = br[t * 16 + (lane & 15)];
    }

    const int r0 = blockIdx.x * 128 + wave * 16;
    int arow = r0 + (lane & 15);
    if (arow >= n_nodes) arow = n_nodes - 1;   // clamped rows feed discarded outputs
    const int kb = (lane >> 4) * 8;

    short8 aggA[2], feaA[2];
    #pragma unroll
    for (int s = 0; s < 2; s++) {
        aggA[s] = *(const short8*)(aggh + (size_t)arow * 128 + s * 32 + kb);
        feaA[s] = *(const short8*)(feats_h + (size_t)arow * 64 + s * 32 + kb);
    }

    #pragma unroll
    for (int t = 0; t < 4; t++) {
        f32x4 c1 = {0.f, 0.f, 0.f, 0.f};
        f32x4 c2 = {0.f, 0.f, 0.f, 0.f};
        c1 = __builtin_amdgcn_mfma_f32_16x16x32_bf16(aggA[0], wf [t],     c1, 0, 0, 0);
        c1 = __builtin_amdgcn_mfma_f32_16x16x32_bf16(aggA[1], wf [4 + t], c1, 0, 0, 0);
        c2 = __builtin_amdgcn_mfma_f32_16x16x32_bf16(feaA[0], wrf[t],     c2, 0, 0, 0);
        c2 = __builtin_amdgcn_mfma_f32_16x16x32_bf16(feaA[1], wrf[4 + t], c2, 0, 0, 0);
        const int col = t * 16 + (lane & 15);
        float ls = 0.f, lq = 0.f;
        #pragma unroll
        for (int r = 0; r < 4; r++) {
            const int row = r0 + (lane >> 4) * 4 + r;
            const float hv = fmaxf(c1[r] + bt[t], 0.f) + fmaxf(c2[r] + brt[t], 0.f);
            if (row < n_nodes) {
                h[(size_t)row * 64 + col] = hv;
                ls += hv;
                lq += hv * hv;
            }
        }
        ls += __shfl_xor(ls, 16); ls += __shfl_xor(ls, 32);
        lq += __shfl_xor(lq, 16); lq += __shfl_xor(lq, 32);
        if ((lane >> 4) == 0) {
            atomicAdd(&ssum[col], ls);
            atomicAdd(&ssq[col], lq);
        }
    }
    __syncthreads();
    if (tid < 64) {
        atomicAdd(&bnacc[tid], ssum[tid]);
        atomicAdd(&bnacc[64 + tid], ssq[tid]);
    }
}

// ---- BN scale/shift + apply in-place ----
__global__ __launch_bounds__(256) void k_bnapply(
    float* __restrict__ h, const float* __restrict__ bnacc,
    const float* __restrict__ gamma, const float* __restrict__ beta,
    int total4, float inv_n)
{
    __shared__ float ssc[64], ssh[64];
    if (threadIdx.x < 64) {
        const int t = threadIdx.x;
        const float mean = bnacc[t] * inv_n;
        const float var  = bnacc[64 + t] * inv_n - mean * mean;  // biased
        const float sc = gamma[t] * rsqrtf(var + 1e-5f);
        ssc[t] = sc;
        ssh[t] = beta[t] - mean * sc;
    }
    __syncthreads();
    for (int i = blockIdx.x * blockDim.x + threadIdx.x; i < total4;
         i += gridDim.x * blockDim.x) {
        float4 v = ((float4*)h)[i];
        const int j = (i & 15) << 2;
        v.x = v.x * ssc[j + 0] + ssh[j + 0];
        v.y = v.y * ssc[j + 1] + ssh[j + 1];
        v.z = v.z * ssc[j + 2] + ssh[j + 2];
        v.w = v.w * ssc[j + 3] + ssh[j + 3];
        ((float4*)h)[i] = v;
    }
}

extern "C" void kernel_launch(void* const* d_in, const int* in_sizes, int n_in,
                              void* d_out, int out_size, void* d_ws, size_t ws_size,
                              hipStream_t stream)
{
    const float* feats = (const float*)d_in[0];
    const int*   src   = (const int*)  d_in[1];
    const int*   dst   = (const int*)  d_in[2];
    const float* W     = (const float*)d_in[3];
    const float* b     = (const float*)d_in[4];
    const float* Wr    = (const float*)d_in[5];
    const float* br    = (const float*)d_in[6];
    const float* gamma = (const float*)d_in[7];
    const float* beta  = (const float*)d_in[8];

    const int n_nodes = in_sizes[0] / 64;            // 100000 (< 2^17)
    const int n_edges = in_sizes[1];
    const int nbkt    = (n_nodes + BKT - 1) / BKT;   // 1563 (<= NBKT_MAX)
    const int nbatch  = (n_edges + PB - 1) / PB;     // 196

    // ws: cursor[2048] | bnacc[128] | pk_slots[nbkt*SCAP u32 ~9.6MB] |
    //     feats_h[N*64 u16 12.8MB] | Wpk[4096 s16] | Wrpk[4096 s16]
    int*      cursor   = (int*)d_ws;
    float*    bnacc    = (float*)(cursor + NBKT_MAX);
    unsigned* pk_slots = (unsigned*)(bnacc + 128);
    unsigned short* feats_h = (unsigned short*)(pk_slots + (size_t)nbkt * SCAP);
    short*    Wpk      = (short*)(feats_h + (size_t)n_nodes * 64);
    short*    Wrpk     = Wpk + 4096;
    unsigned short* aggh = (unsigned short*)d_out;   // bf16 agg in d_out row-slots
    float*    h        = (float*)d_out;

    // zero cursor + bnacc (contiguous)
    hipMemsetAsync(cursor, 0, (size_t)(NBKT_MAX + 128) * sizeof(int), stream);

    k_prep_part<<<nbatch + CAST_BLKS + 1, 1024, 0, stream>>>(
        src, dst, cursor, pk_slots, n_edges, nbatch, nbkt,
        feats, feats_h, n_nodes * 8, W, Wr, Wpk, Wrpk);
    k_gsort<<<nbkt, 512, 0, stream>>>(feats_h, cursor, pk_slots, aggh, n_nodes);
    k_mv   <<<(n_nodes + 127) / 128, 512, 0, stream>>>(aggh, feats_h, Wpk, Wrpk,
                                                       b, br, h, bnacc, n_nodes);
    k_bnapply<<<2048, 256, 0, stream>>>(h, bnacc, gamma, beta, n_nodes * 16,
                                        1.f / (float)n_nodes);
}

// Round 12
// 98.194 us; speedup vs baseline: 1.3967x; 1.0308x over previous
//
#include <hip/hip_runtime.h>
#include <hip/hip_bf16.h>

// GCN layer: agg = segment_sum(feats[src], dst); h = relu(agg@W+b) + relu(feats@Wr+br);
// out = batchnorm(h) over node dim (biased var, eps=1e-5) * gamma + beta.
// N=100000 nodes, E=1600000 edges, F=64.
//
// R12 = R11 + bf16 h intermediate: each 256B d_out slot = [aggh bf16 x64 | h bf16 x64];
// mv reads slot first-half, writes second-half (disjoint -> no aliasing hazard);
// bnapply reads bf16 h, writes f32 out over the full slot (read-before-write within
// the owning wave). Cuts mv+bn traffic 76.8 -> 51.2 MB. BN stats still f32-exact.

typedef __attribute__((ext_vector_type(8))) short short8;
typedef __attribute__((ext_vector_type(4))) float f32x4;

constexpr int BKT  = 64;           // nodes per bucket (dloc 6 bits | src 17 bits)
constexpr int NBKT_MAX = 2048;
constexpr int SCAP = 1536;         // per-bucket slot capacity (mean 1024)
constexpr int PB   = 8192;         // edges per partition batch
constexpr int CAST_BLKS = 800;     // 800 x 1024 threads >= 800000 short8 groups

static __device__ __forceinline__ float bfbits_lo(unsigned u) {
    union { unsigned u; float f; } c; c.u = u << 16; return c.f;
}
static __device__ __forceinline__ float bfbits_hi(unsigned u) {
    union { unsigned u; float f; } c; c.u = u & 0xffff0000u; return c.f;
}
static __device__ __forceinline__ short bf16r(float x) {
    __hip_bfloat16 h = __float2bfloat16(x);   // RNE
    union { __hip_bfloat16 h; short s; } c; c.h = h; return c.s;
}
static __device__ __forceinline__ unsigned bf16pair(float x, float y) {
    return (unsigned)(unsigned short)bf16r(x) | ((unsigned)(unsigned short)bf16r(y) << 16);
}

// ---- fused prep+partition (role-split blocks, all 1024 threads) ----
// blocks [0,nbatch): partition edges into fixed bucket slots (register-staged)
// blocks [nbatch, nbatch+CAST_BLKS): feats fp32->bf16
// block  nbatch+CAST_BLKS: W/Wr MFMA B-fragment pack
__global__ __launch_bounds__(1024) void k_prep_part(
    const int* __restrict__ src, const int* __restrict__ dst,
    int* __restrict__ cursor, unsigned* __restrict__ pk_slots,
    int n_edges, int nbatch, int nbkt,
    const float* __restrict__ feats, unsigned short* __restrict__ feats_h, int total8,
    const float* __restrict__ W, const float* __restrict__ Wr,
    short* __restrict__ Wpk, short* __restrict__ Wrpk)
{
    __shared__ int hist[NBKT_MAX], basei[NBKT_MAX], cnt2[NBKT_MAX];
    const int bid = blockIdx.x;
    const int tid = threadIdx.x;
    if (bid < nbatch) {
        const int e0 = bid * PB;
        for (int i = tid; i < nbkt; i += 1024) { hist[i] = 0; cnt2[i] = 0; }
        __syncthreads();
        unsigned pk[8]; unsigned short bb8[8];
        #pragma unroll
        for (int i = 0; i < 8; i++) {
            const int e = e0 + i * 1024 + tid;
            if (e < n_edges) {
                const int d = dst[e];
                const int s = src[e];
                const int bb = d >> 6;
                bb8[i] = (unsigned short)bb;
                pk[i] = ((unsigned)(d & 63) << 17) | (unsigned)s;
                atomicAdd(&hist[bb], 1);
            } else bb8[i] = 0xffff;
        }
        __syncthreads();
        for (int i = tid; i < nbkt; i += 1024) {
            const int c = hist[i];
            basei[i] = (c > 0) ? atomicAdd(&cursor[i], c) : 0;
        }
        __syncthreads();
        #pragma unroll
        for (int i = 0; i < 8; i++) {
            if (bb8[i] != 0xffff) {
                const int bb = bb8[i];
                const int pos = basei[bb] + atomicAdd(&cnt2[bb], 1);
                if (pos < SCAP)                       // overflow guard (never in practice)
                    pk_slots[(size_t)bb * SCAP + pos] = pk[i];
            }
        }
    } else if (bid < nbatch + CAST_BLKS) {
        const int cb = bid - nbatch;
        for (int i = cb * 1024 + tid; i < total8; i += CAST_BLKS * 1024) {
            float4 v0 = ((const float4*)feats)[i * 2];
            float4 v1 = ((const float4*)feats)[i * 2 + 1];
            short8 o;
            o[0] = bf16r(v0.x); o[1] = bf16r(v0.y); o[2] = bf16r(v0.z); o[3] = bf16r(v0.w);
            o[4] = bf16r(v1.x); o[5] = bf16r(v1.y); o[6] = bf16r(v1.z); o[7] = bf16r(v1.w);
            ((short8*)feats_h)[i] = o;
        }
    } else {
        // pack W/Wr into MFMA B-fragment layout (verified R3):
        // packed[((s*4+t)*64+lane)*8+j] = W[(s*32+(lane>>4)*8+j)*64 + (t*16+(lane&15))]
        for (int idx = tid; idx < 8192; idx += 1024) {
            const int m = idx >> 12;
            const int rem = idx & 4095;
            const int j = rem & 7;
            const int q = rem >> 3;
            const int lane = q & 63;
            const int st = q >> 6;
            const int s = st >> 2;
            const int t = st & 3;
            const int k = s * 32 + (lane >> 4) * 8 + j;
            const int n = t * 16 + (lane & 15);
            const float v = (m == 0) ? W[k * 64 + n] : Wr[k * 64 + n];
            short* out = (m == 0) ? Wpk : Wrpk;
            out[rem] = bf16r(v);
        }
    }
}

// ---- fused per-bucket node-sort + gather: 512 thr (8 waves), 4 blocks/CU ----
// Sorts the bucket's ~1024 edges to per-node lists in LDS, then wave w gathers
// nodes w*8..w*8+7: each edge read by 16 lanes x uint2 (8B), 4 edge-slots/wave.
// Writes bf16 agg rows into d_out slot FIRST halves (128B of each 256B slot).
__global__ __launch_bounds__(512) void k_gsort(
    const unsigned short* __restrict__ feats_h, const int* __restrict__ cursor,
    const unsigned* __restrict__ pk_slots, unsigned short* __restrict__ aggh,
    int n_nodes)
{
    __shared__ unsigned raw[SCAP];        // 6 KB
    __shared__ unsigned srt[SCAP];        // 6 KB
    __shared__ int cnt[BKT], cnt2[BKT], noff[BKT + 1];
    const int bkt = blockIdx.x;
    const int tid = threadIdx.x;
    int m = cursor[bkt]; if (m > SCAP) m = SCAP;
    const unsigned* gsl = pk_slots + (size_t)bkt * SCAP;

    if (tid < BKT) { cnt[tid] = 0; cnt2[tid] = 0; }
    __syncthreads();
    for (int i = tid; i < m; i += 512) {
        const unsigned p = gsl[i];
        raw[i] = p;
        atomicAdd(&cnt[p >> 17], 1);
    }
    __syncthreads();
    if (tid < 64) {                       // wave-0 inclusive shfl scan over 64 bins
        int v = cnt[tid];
        #pragma unroll
        for (int off = 1; off < 64; off <<= 1) {
            const int y = __shfl_up(v, off);
            if (tid >= off) v += y;
        }
        noff[tid + 1] = v;
        if (tid == 0) noff[0] = 0;
    }
    __syncthreads();
    for (int i = tid; i < m; i += 512) {
        const unsigned p = raw[i];
        const int d = p >> 17;
        srt[noff[d] + atomicAdd(&cnt2[d], 1)] = p & 0x1ffffu;
    }
    __syncthreads();

    // gather: 8 nodes per wave; 16 lanes x 8B per edge, 4 edge slots
    const int wave = tid >> 6;
    const int lane = tid & 63;
    const int slot = lane >> 4;           // edge slot 0..3
    const int q    = lane & 15;           // column group: cols 4q..4q+3
    #pragma unroll 1
    for (int k = 0; k < 8; k++) {
        const int nl = wave * 8 + k;
        const int n  = bkt * BKT + nl;
        if (n >= n_nodes) break;
        const int beg = noff[nl], end = noff[nl + 1];
        float a0 = 0.f, a1 = 0.f, a2 = 0.f, a3 = 0.f;
        int base = beg;
        for (; base + 16 <= end; base += 16) {      // unmasked: 4 groups x 4 edges
            #pragma unroll
            for (int g = 0; g < 4; g++) {
                const unsigned s = srt[base + 4 * g + slot];
                const uint2 v = *(const uint2*)(feats_h + (size_t)s * 64 + q * 4);
                a0 += bfbits_lo(v.x); a1 += bfbits_hi(v.x);
                a2 += bfbits_lo(v.y); a3 += bfbits_hi(v.y);
            }
        }
        if (base < end) {                           // single masked tail block
            #pragma unroll
            for (int g = 0; g < 4; g++) {
                const int e = base + 4 * g + slot;
                const bool vd = e < end;
                const unsigned s = srt[vd ? e : beg];
                const uint2 v = *(const uint2*)(feats_h + (size_t)s * 64 + q * 4);
                a0 += vd ? bfbits_lo(v.x) : 0.f;
                a1 += vd ? bfbits_hi(v.x) : 0.f;
                a2 += vd ? bfbits_lo(v.y) : 0.f;
                a3 += vd ? bfbits_hi(v.y) : 0.f;
            }
        }
        a0 += __shfl_xor(a0, 16); a0 += __shfl_xor(a0, 32);
        a1 += __shfl_xor(a1, 16); a1 += __shfl_xor(a1, 32);
        a2 += __shfl_xor(a2, 16); a2 += __shfl_xor(a2, 32);
        a3 += __shfl_xor(a3, 16); a3 += __shfl_xor(a3, 32);
        if (slot == 0) {
            uint2 o;
            o.x = bf16pair(a0, a1);
            o.y = bf16pair(a2, a3);
            *(uint2*)(aggh + (size_t)n * 128 + q * 4) = o;   // 8B aligned
        }
    }
}

// ---- dual matvec via MFMA + relu + residual + BN partials ----
// Slot layout on d_out: [aggh bf16 x64 | h bf16 x64] per row. mv reads the first
// half, writes the second half -> disjoint, no ordering hazard.
__global__ __launch_bounds__(512) void k_mv(
    unsigned short* hb, const unsigned short* __restrict__ feats_h,
    const short* __restrict__ Wpk, const short* __restrict__ Wrpk,
    const float* __restrict__ b, const float* __restrict__ br,
    float* __restrict__ bnacc, int n_nodes)
{
    __shared__ float ssum[64], ssq[64];
    const int tid = threadIdx.x;
    const int wave = tid >> 6;
    const int lane = tid & 63;
    if (tid < 64) { ssum[tid] = 0.f; ssq[tid] = 0.f; }
    __syncthreads();

    short8 wf[8], wrf[8];
    #pragma unroll
    for (int i = 0; i < 8; i++) {
        wf[i]  = *(const short8*)(Wpk  + (i * 64 + lane) * 8);
        wrf[i] = *(const short8*)(Wrpk + (i * 64 + lane) * 8);
    }
    float bt[4], brt[4];
    #pragma unroll
    for (int t = 0; t < 4; t++) {
        bt[t]  = b [t * 16 + (lane & 15)];
        brt[t] = br[t * 16 + (lane & 15)];
    }

    const int r0 = blockIdx.x * 128 + wave * 16;
    int arow = r0 + (lane & 15);
    if (arow >= n_nodes) arow = n_nodes - 1;   // clamped rows feed discarded outputs
    const int kb = (lane >> 4) * 8;

    short8 aggA[2], feaA[2];
    #pragma unroll
    for (int s = 0; s < 2; s++) {
        aggA[s] = *(const short8*)(hb + (size_t)arow * 128 + s * 32 + kb);
        feaA[s] = *(const short8*)(feats_h + (size_t)arow * 64 + s * 32 + kb);
    }

    #pragma unroll
    for (int t = 0; t < 4; t++) {
        f32x4 c1 = {0.f, 0.f, 0.f, 0.f};
        f32x4 c2 = {0.f, 0.f, 0.f, 0.f};
        c1 = __builtin_amdgcn_mfma_f32_16x16x32_bf16(aggA[0], wf [t],     c1, 0, 0, 0);
        c1 = __builtin_amdgcn_mfma_f32_16x16x32_bf16(aggA[1], wf [4 + t], c1, 0, 0, 0);
        c2 = __builtin_amdgcn_mfma_f32_16x16x32_bf16(feaA[0], wrf[t],     c2, 0, 0, 0);
        c2 = __builtin_amdgcn_mfma_f32_16x16x32_bf16(feaA[1], wrf[4 + t], c2, 0, 0, 0);
        const int col = t * 16 + (lane & 15);
        float ls = 0.f, lq = 0.f;
        #pragma unroll
        for (int r = 0; r < 4; r++) {
            const int row = r0 + (lane >> 4) * 4 + r;
            const float hv = fmaxf(c1[r] + bt[t], 0.f) + fmaxf(c2[r] + brt[t], 0.f);
            if (row < n_nodes) {
                hb[(size_t)row * 128 + 64 + col] = (unsigned short)bf16r(hv);
                ls += hv;
                lq += hv * hv;
            }
        }
        ls += __shfl_xor(ls, 16); ls += __shfl_xor(ls, 32);
        lq += __shfl_xor(lq, 16); lq += __shfl_xor(lq, 32);
        if ((lane >> 4) == 0) {
            atomicAdd(&ssum[col], ls);
            atomicAdd(&ssq[col], lq);
        }
    }
    __syncthreads();
    if (tid < 64) {
        atomicAdd(&bnacc[tid], ssum[tid]);
        atomicAdd(&bnacc[64 + tid], ssq[tid]);
    }
}

// ---- BN scale/shift + apply: read bf16 h (slot 2nd half), write f32 full slot ----
// One wave per 4 rows per iteration; the f32 store depends on the bf16 load, so
// the wave's reads complete before its overlapping writes issue.
__global__ __launch_bounds__(256) void k_bnapply(
    const unsigned short* hb, float* out,
    const float* __restrict__ bnacc, const float* __restrict__ gamma,
    const float* __restrict__ beta, int n_nodes, float inv_n)
{
    __shared__ float ssc[64], ssh[64];
    if (threadIdx.x < 64) {
        const int t = threadIdx.x;
        const float mean = bnacc[t] * inv_n;
        const float var  = bnacc[64 + t] * inv_n - mean * mean;  // biased
        const float sc = gamma[t] * rsqrtf(var + 1e-5f);
        ssc[t] = sc;
        ssh[t] = beta[t] - mean * sc;
    }
    __syncthreads();
    const int lane = threadIdx.x & 63;
    const int q    = lane & 15;       // col group: cols 4q..4q+3
    const int rsub = lane >> 4;       // row within 4-row group
    const int gwave = (blockIdx.x * 256 + threadIdx.x) >> 6;
    const int nwave = (gridDim.x * 256) >> 6;
    const int nrg   = (n_nodes + 3) >> 2;
    const float4 sc4 = *(const float4*)&ssc[q * 4];
    const float4 sh4 = *(const float4*)&ssh[q * 4];
    for (int rg = gwave; rg < nrg; rg += nwave) {
        const int r = rg * 4 + rsub;
        if (r >= n_nodes) continue;
        const uint2 v = *(const uint2*)(hb + (size_t)r * 128 + 64 + q * 4);
        float4 o;
        o.x = bfbits_lo(v.x) * sc4.x + sh4.x;
        o.y = bfbits_hi(v.x) * sc4.y + sh4.y;
        o.z = bfbits_lo(v.y) * sc4.z + sh4.z;
        o.w = bfbits_hi(v.y) * sc4.w + sh4.w;
        *(float4*)(out + (size_t)r * 64 + q * 4) = o;
    }
}

extern "C" void kernel_launch(void* const* d_in, const int* in_sizes, int n_in,
                              void* d_out, int out_size, void* d_ws, size_t ws_size,
                              hipStream_t stream)
{
    const float* feats = (const float*)d_in[0];
    const int*   src   = (const int*)  d_in[1];
    const int*   dst   = (const int*)  d_in[2];
    const float* W     = (const float*)d_in[3];
    const float* b     = (const float*)d_in[4];
    const float* Wr    = (const float*)d_in[5];
    const float* br    = (const float*)d_in[6];
    const float* gamma = (const float*)d_in[7];
    const float* beta  = (const float*)d_in[8];

    const int n_nodes = in_sizes[0] / 64;            // 100000 (< 2^17)
    const int n_edges = in_sizes[1];
    const int nbkt    = (n_nodes + BKT - 1) / BKT;   // 1563 (<= NBKT_MAX)
    const int nbatch  = (n_edges + PB - 1) / PB;     // 196

    // ws: cursor[2048] | bnacc[128] | pk_slots[nbkt*SCAP u32 ~9.6MB] |
    //     feats_h[N*64 u16 12.8MB] | Wpk[4096 s16] | Wrpk[4096 s16]
    int*      cursor   = (int*)d_ws;
    float*    bnacc    = (float*)(cursor + NBKT_MAX);
    unsigned* pk_slots = (unsigned*)(bnacc + 128);
    unsigned short* feats_h = (unsigned short*)(pk_slots + (size_t)nbkt * SCAP);
    short*    Wpk      = (short*)(feats_h + (size_t)n_nodes * 64);
    short*    Wrpk     = Wpk + 4096;
    unsigned short* hb = (unsigned short*)d_out;     // slot: [agg bf16 x64 | h bf16 x64]
    float*    out      = (float*)d_out;

    // zero cursor + bnacc (contiguous)
    hipMemsetAsync(cursor, 0, (size_t)(NBKT_MAX + 128) * sizeof(int), stream);

    k_prep_part<<<nbatch + CAST_BLKS + 1, 1024, 0, stream>>>(
        src, dst, cursor, pk_slots, n_edges, nbatch, nbkt,
        feats, feats_h, n_nodes * 8, W, Wr, Wpk, Wrpk);
    k_gsort<<<nbkt, 512, 0, stream>>>(feats_h, cursor, pk_slots, hb, n_nodes);
    k_mv   <<<(n_nodes + 127) / 128, 512, 0, stream>>>(hb, feats_h, Wpk, Wrpk,
                                                       b, br, bnacc, n_nodes);
    k_bnapply<<<2048, 256, 0, stream>>>(hb, out, bnacc, gamma, beta, n_nodes,
                                        1.f / (float)n_nodes);
}